// Round 12
// baseline (6352.782 us; speedup 1.0000x reference)
//
#include <hip/hip_runtime.h>
#include <cstdint>
#include <cstddef>

#define BB 16
#define LL 2048
#define HME 48
#define GH 192
#define DMODEL 96
#define EDIM 768
#define NST 32

static __device__ __forceinline__ float fsig(float x) { return 1.f / (1.f + __expf(-x)); }
static __device__ __forceinline__ float ftanh(float x) { return 1.f - 2.f / (__expf(2.f * x) + 1.f); }
static __device__ __forceinline__ float siluf_(float x) { return x / (1.f + __expf(-x)); }

static __device__ __forceinline__ float rlane(float v, int i) {
    return __int_as_float(__builtin_amdgcn_readlane(__float_as_int(v), i));
}

static __device__ __forceinline__ void gload_lds16(const float* g, float* s) {
    __builtin_amdgcn_global_load_lds(
        (const __attribute__((address_space(1))) void*)g,
        (__attribute__((address_space(3))) void*)s, 16, 0, 0);
}

// ---------------------------------------------------------------- diag
__global__ void diag_k(float* o, int n, float v) {
    int i = blockIdx.x * 64 + threadIdx.x;
    if (i < n) o[i] = v;
}

// ---------------------------------------------------------------- GEMM
// emode 0: C = acc (+bias) (+res);  emode 1: C = res * silu(acc)
// Ahat[m][k] = A[m][k] * (RS ? RS[m]*NW[k] : 1)
#define GBM 128
#define GBN 128
#define GBK 16
__global__ __launch_bounds__(256) void gemm_bt(
    const float* __restrict__ A, size_t lda, size_t zsA,
    const float* __restrict__ W,
    const float* __restrict__ bias,
    const float* __restrict__ res,
    const float* __restrict__ RS, size_t zsRS,
    const float* __restrict__ NW,
    float* __restrict__ C, size_t ldc, size_t zsC,
    int M, int N, int K, int emode)
{
    A += (size_t)blockIdx.z * zsA;
    C += (size_t)blockIdx.z * zsC;
    if (RS) RS += (size_t)blockIdx.z * zsRS;
    __shared__ __align__(16) float As[GBK][GBM + 4];
    __shared__ __align__(16) float Ws[GBK][GBN + 4];
    int bm = blockIdx.x * GBM, bn = blockIdx.y * GBN;
    int tid = threadIdx.x;
    int tx = tid & 15, ty = tid >> 4;
    int lk = tid & 15;
    int lm = tid >> 4;
    float acc[8][8] = {};
    for (int k0 = 0; k0 < K; k0 += GBK) {
        #pragma unroll
        for (int p = 0; p < 8; ++p) {
            int m = lm + p * 16;
            int gm = bm + m, gk = k0 + lk;
            float aval = 0.f;
            if (gm < M && gk < K) {
                aval = A[(size_t)gm * lda + gk];
                if (RS) aval *= RS[gm] * NW[gk];
            }
            As[lk][m] = aval;
            int gn = bn + m;
            Ws[lk][m] = (gn < N && gk < K) ? W[(size_t)gn * K + gk] : 0.f;
        }
        __syncthreads();
        #pragma unroll
        for (int k = 0; k < GBK; ++k) {
            float av[8], bv[8];
            #pragma unroll
            for (int i = 0; i < 8; i += 4) {
                float4 t4 = *(const float4*)&As[k][ty * 8 + i];
                av[i] = t4.x; av[i+1] = t4.y; av[i+2] = t4.z; av[i+3] = t4.w;
            }
            #pragma unroll
            for (int jj = 0; jj < 8; jj += 4) {
                float4 t4 = *(const float4*)&Ws[k][tx * 8 + jj];
                bv[jj] = t4.x; bv[jj+1] = t4.y; bv[jj+2] = t4.z; bv[jj+3] = t4.w;
            }
            #pragma unroll
            for (int i = 0; i < 8; ++i)
                #pragma unroll
                for (int jj = 0; jj < 8; ++jj)
                    acc[i][jj] = fmaf(av[i], bv[jj], acc[i][jj]);
        }
        __syncthreads();
    }
    #pragma unroll
    for (int i = 0; i < 8; ++i) {
        int gm = bm + ty * 8 + i;
        if (gm >= M) continue;
        #pragma unroll
        for (int jj = 0; jj < 8; ++jj) {
            int gn = bn + tx * 8 + jj;
            if (gn >= N) continue;
            float v = acc[i][jj];
            if (emode == 0) {
                if (bias) v += bias[gn];
                if (res)  v += res[(size_t)gm * ldc + gn];
            } else {
                v = res[(size_t)gm * ldc + gn] * siluf_(v);
            }
            C[(size_t)gm * ldc + gn] = v;
        }
    }
}

// ---------------------------------------------------------------- fused rmsnorm + in_proj(half1) + causal conv K=16 + silu
// grid (LL/64, EDIM/64, BB), 320 threads (5 waves).
// Per block: xm_raw[80 t-rows x 64 n-cols] = (RS*NW*H2)[t0-15..t0+64] @ ipw.T
// computed into LDS, then depthwise conv+bias+silu -> XMo (64 t x 64 n).
// Replaces 16 serial per-batch GEMM launches + 16 conv launches + the SH
// xm round-trip (~220 MB HBM).
__global__ __launch_bounds__(320) void ipconv_k(
    const float* __restrict__ H2,    // [B][L][96]
    const float* __restrict__ RS,    // [B][L]
    const float* __restrict__ NW,    // [96]
    const float* __restrict__ IPW,   // [768][96]
    const float* __restrict__ cw,    // [768][16]
    const float* __restrict__ cb,    // [768]
    float* __restrict__ XMo)         // [B][L][768]
{
    __shared__ __align__(16) float As[96][84];   // [k][row], 80 rows used
    __shared__ __align__(16) float Ws[96][68];   // [k][col], 64 cols used
    __shared__ __align__(16) float xs[80][68];   // xm_raw tile
    __shared__ float wsh[64][17];
    int t0 = blockIdx.x * 64, n0 = blockIdx.y * 64, b = blockIdx.z;
    int tid = threadIdx.x;

    // stage A tile: rows r=0..79 -> global t = t0-15+r (0 outside [0,L))
    for (int idx = tid; idx < 80 * 96; idx += 320) {
        int r = idx / 96, k = idx % 96;
        int gt = t0 - 15 + r;
        float v = 0.f;
        if (gt >= 0 && gt < LL) {
            size_t row = (size_t)b * LL + gt;
            v = H2[row * 96 + k] * RS[row] * NW[k];
        }
        As[k][r] = v;
    }
    // stage W tile
    for (int idx = tid; idx < 64 * 96; idx += 320) {
        int c = idx / 96, k = idx % 96;
        Ws[k][c] = IPW[(size_t)(n0 + c) * 96 + k];
    }
    // stage conv weights
    for (int idx = tid; idx < 64 * 16; idx += 320)
        wsh[idx >> 4][idx & 15] = cw[(size_t)(n0 + (idx >> 4)) * 16 + (idx & 15)];
    __syncthreads();

    // GEMM: thread (rg,cg) computes rows 4rg..+3 x cols 4cg..+3
    {
        int rg = tid >> 4, cg = tid & 15;     // rg 0..19, cg 0..15
        float acc[4][4] = {};
        #pragma unroll 4
        for (int k = 0; k < 96; ++k) {
            float4 a4 = *(const float4*)&As[k][4 * rg];
            float4 w4 = *(const float4*)&Ws[k][4 * cg];
            float av[4] = {a4.x, a4.y, a4.z, a4.w};
            float wv[4] = {w4.x, w4.y, w4.z, w4.w};
            #pragma unroll
            for (int i = 0; i < 4; ++i)
                #pragma unroll
                for (int j = 0; j < 4; ++j)
                    acc[i][j] = fmaf(av[i], wv[j], acc[i][j]);
        }
        #pragma unroll
        for (int i = 0; i < 4; ++i)
            *(float4*)&xs[4 * rg + i][4 * cg] =
                make_float4(acc[i][0], acc[i][1], acc[i][2], acc[i][3]);
    }
    __syncthreads();

    // conv + bias + silu (first 256 threads; xs rows 0..78 = t0-15..t0+63)
    if (tid < 256) {
        int cl = tid & 63, ts = tid >> 6;
        float bias = cb[n0 + cl];
        for (int i = 0; i < 16; ++i) {
            int tl = ts * 16 + i;
            float acc = bias;
            #pragma unroll
            for (int k = 0; k < 16; ++k) acc = fmaf(wsh[cl][k], xs[tl + k][cl], acc);
            XMo[((size_t)b * LL + t0 + tl) * EDIM + n0 + cl] = siluf_(acc);
        }
    }
}

// ---------------------------------------------------------------- LSTM scan v10
// v9 + micro-ILP: readlanes batched x4 into distinct temps and each gate split
// into 2 partial accumulators (breaks SGPR WAR serialization between readlane
// and consuming FMA); branchless q-prefetch so LDS loads hoist early.
__global__ __launch_bounds__(64)
__attribute__((amdgpu_waves_per_eu(1, 1)))
void lstm_scan(
    const float* __restrict__ xg,        // [2][B][L][192]
    const float* __restrict__ WhhF, const float* __restrict__ bhhF,
    const float* __restrict__ WhhB, const float* __restrict__ bhhB,
    float* __restrict__ hout)            // [B][L][96]
{
    __shared__ __align__(16) float xs[2][64 * GH];   // 96 KB
    int blk = blockIdx.x;
    int b = blk >> 1, d = blk & 1;
    const float* W  = d ? WhhB : WhhF;
    const float* bh = d ? bhhB : bhhF;
    int l = threadIdx.x;

    float w0[HME], w1[HME], w2[HME];
    #pragma unroll
    for (int i = 0; i < HME; i += 4) {
        float4 t;
        t = *(const float4*)(W + (size_t)l * HME + i);
        w0[i] = t.x; w0[i+1] = t.y; w0[i+2] = t.z; w0[i+3] = t.w;
        t = *(const float4*)(W + (size_t)(64 + l) * HME + i);
        w1[i] = t.x; w1[i+1] = t.y; w1[i+2] = t.z; w1[i+3] = t.w;
        t = *(const float4*)(W + (size_t)(128 + l) * HME + i);
        w2[i] = t.x; w2[i+1] = t.y; w2[i+2] = t.z; w2[i+3] = t.w;
    }
    float b0 = bh[l], b1 = bh[64 + l], b2 = bh[128 + l];

    const float* xgp = xg + (size_t)(d * BB + b) * LL * GH;
    float hh = 0.f, c = 0.f;

    int sf = (l < 16) ? (48 + l) : (l - 16);
    int sg = (l < 32) ? (32 + l) : (l - 32);
    int so_ = (16 + l) & 63;

    const int NCHK = LL / 64;            // 32

    {
        const float* src = xgp + (size_t)(d ? (LL - 64) : 0) * GH;
        #pragma unroll
        for (int k = 0; k < 48; ++k)
            gload_lds16(src + k * 256 + l * 4, &xs[0][k * 256]);
    }
    asm volatile("s_waitcnt vmcnt(0)");
    __syncthreads();

    for (int cc = 0; cc < NCHK; ++cc) {
        const float* xc = &xs[cc & 1][0];
        if (cc + 1 < NCHK) {
            const float* src = xgp + (size_t)(d ? (LL - 64 * (cc + 2)) : (64 * (cc + 1))) * GH;
            float* dst = &xs[(cc + 1) & 1][0];
            #pragma unroll
            for (int k = 0; k < 48; ++k)
                gload_lds16(src + k * 256 + l * 4, dst + k * 256);
        }
        int bs = d ? (LL - 64 * (cc + 1)) : (64 * cc);
        int toff = d ? 63 : 0;
        int dt = d ? -1 : 1;
        float q0 = xc[toff * GH + l];
        float q1 = xc[toff * GH + 64 + l];
        float q2 = xc[toff * GH + 128 + l];
        for (int s = 0; s < 64; ++s) {
            float g0 = q0 + b0, g1 = q1 + b1, g2 = q2 + b2;
            float g0b = 0.f, g1b = 0.f, g2b = 0.f;
            int tn = (toff + dt) & 63;          // branchless prefetch (wraps on last step; discarded)
            q0 = xc[tn * GH + l];
            q1 = xc[tn * GH + 64 + l];
            q2 = xc[tn * GH + 128 + l];
            #pragma unroll
            for (int i = 0; i < HME; i += 4) {
                float hv0 = rlane(hh, i);
                float hv1 = rlane(hh, i + 1);
                float hv2 = rlane(hh, i + 2);
                float hv3 = rlane(hh, i + 3);
                g0  = fmaf(w0[i],     hv0, g0 );
                g1  = fmaf(w1[i],     hv0, g1 );
                g2  = fmaf(w2[i],     hv0, g2 );
                g0b = fmaf(w0[i + 1], hv1, g0b);
                g1b = fmaf(w1[i + 1], hv1, g1b);
                g2b = fmaf(w2[i + 1], hv1, g2b);
                g0  = fmaf(w0[i + 2], hv2, g0 );
                g1  = fmaf(w1[i + 2], hv2, g1 );
                g2  = fmaf(w2[i + 2], hv2, g2 );
                g0b = fmaf(w0[i + 3], hv3, g0b);
                g1b = fmaf(w1[i + 3], hv3, g1b);
                g2b = fmaf(w2[i + 3], hv3, g2b);
            }
            g0 += g0b; g1 += g1b; g2 += g2b;
            float a0 = fsig(g0);
            float a1 = (l < 32) ? fsig(g1) : ftanh(g1);
            float a2 = (l < 16) ? ftanh(g2) : fsig(g2);
            float gfA = __shfl(a0, sf);
            float gfB = __shfl(a1, sf);
            float ggA = __shfl(a1, sg);
            float ggB = __shfl(a2, sg);
            float go  = __shfl(a2, so_);
            float gf = (l < 16) ? gfA : gfB;
            float gg = (l < 32) ? ggA : ggB;
            c = fmaf(gf, c, a0 * gg);
            hh = go * ftanh(c);
            if (l < HME)
                hout[((size_t)b * LL + bs + toff) * DMODEL + d * HME + l] = hh;
            toff += dt;
        }
        asm volatile("s_waitcnt vmcnt(0)");
        __syncthreads();
    }
}

// ---------------------------------------------------------------- RMS per-row scale
__global__ __launch_bounds__(256) void rms_rs_k(
    const float* __restrict__ X, float* __restrict__ RS)
{
    int row = blockIdx.x * 4 + (threadIdx.x >> 6);
    int lane = threadIdx.x & 63;
    const float* xr = X + (size_t)row * DMODEL;
    float v0 = xr[lane];
    float v1 = (lane < 32) ? xr[64 + lane] : 0.f;
    float s = v0 * v0 + v1 * v1;
    #pragma unroll
    for (int dd = 1; dd < 64; dd <<= 1) s += __shfl_xor(s, dd);
    if (lane == 0) RS[row] = 1.f / sqrtf(s * (1.f / 96.f) + 1e-5f);
}

// ---------------------------------------------------------------- selective scan v3
#define SCH 16
__global__ __launch_bounds__(256) void scan_k(
    const float* __restrict__ XM,    // [B][L][768]
    const float* __restrict__ DBC,   // [B][L][70]
    const float* __restrict__ dpw,   // [768][6]
    const float* __restrict__ dpb,   // [768]
    const float* __restrict__ Alog,  // [768][32]
    const float* __restrict__ Dp,    // [768]
    float* Y)                        // [B][L][768]
{
    __shared__ float xs[2][SCH][64];
    __shared__ float dsh[2][SCH][72];
    int tid = threadIdx.x;
    int lane = tid & 63, wv = tid >> 6;
    int esub = lane & 15, nl = lane >> 4, n0 = nl * 8;
    int ch0 = blockIdx.x * 64;
    int b = ch0 / EDIM;
    int ebase = ch0 % EDIM;
    int e = ebase + wv * 16 + esub;

    float An[8], h[8], dw[6];
    #pragma unroll
    for (int i = 0; i < 8; ++i) { An[i] = -expf(Alog[(size_t)e * NST + n0 + i]); h[i] = 0.f; }
    #pragma unroll
    for (int r = 0; r < 6; ++r) dw[r] = dpw[(size_t)e * 6 + r];
    float db = dpb[e], Dpe = Dp[e];

    const float* xbase = XM  + ((size_t)b * LL) * EDIM + ebase;
    const float* dbase = DBC + ((size_t)b * LL) * 70;
    float* ybase = Y + ((size_t)b * LL) * EDIM + e;

    int srow = tid >> 4, scol = (tid & 15) * 4;
    float4 px;
    float pd[5];

    px = *(const float4*)(xbase + (size_t)srow * EDIM + scol);
    #pragma unroll
    for (int k = 0; k < 5; ++k) {
        int i = tid + k * 256;
        pd[k] = (i < SCH * 70) ? dbase[i] : 0.f;
    }
    *(float4*)&xs[0][srow][scol] = px;
    #pragma unroll
    for (int k = 0; k < 5; ++k) {
        int i = tid + k * 256;
        if (i < SCH * 70) dsh[0][i / 70][i % 70] = pd[k];
    }
    __syncthreads();

    const int NCH = LL / SCH;   // 128
    for (int cc = 0; cc < NCH; ++cc) {
        int buf = cc & 1;
        if (cc + 1 < NCH) {
            size_t t0n = (size_t)(cc + 1) * SCH;
            px = *(const float4*)(xbase + (t0n + srow) * EDIM + scol);
            #pragma unroll
            for (int k = 0; k < 5; ++k) {
                int i = tid + k * 256;
                pd[k] = (i < SCH * 70) ? dbase[t0n * 70 + i] : 0.f;
            }
        }
        #pragma unroll 2
        for (int tl = 0; tl < SCH; ++tl) {
            const float* drow = &dsh[buf][tl][0];
            float x = xs[buf][tl][wv * 16 + esub];
            float draw = db;
            #pragma unroll
            for (int r = 0; r < 6; ++r) draw = fmaf(dw[r], drow[r], draw);
            float delta = (draw > 20.f) ? draw : __logf(1.f + __expf(draw));
            float dx = delta * x;
            float y = 0.f;
            #pragma unroll
            for (int i = 0; i < 8; ++i) {
                float Bn = drow[6 + n0 + i];
                float Cn = drow[38 + n0 + i];
                float dA = __expf(delta * An[i]);
                h[i] = fmaf(dA, h[i], dx * Bn);
                y = fmaf(h[i], Cn, y);
            }
            y += __shfl_xor(y, 16);
            y += __shfl_xor(y, 32);
            if (nl == 0) ybase[(size_t)(cc * SCH + tl) * EDIM] = fmaf(x, Dpe, y);
        }
        if (cc + 1 < NCH) {
            *(float4*)&xs[buf ^ 1][srow][scol] = px;
            #pragma unroll
            for (int k = 0; k < 5; ++k) {
                int i = tid + k * 256;
                if (i < SCH * 70) dsh[buf ^ 1][i / 70][i % 70] = pd[k];
            }
        }
        __syncthreads();
    }
}

// ---------------------------------------------------------------- host
extern "C" void kernel_launch(void* const* d_in, const int* in_sizes, int n_in,
                              void* d_out, int out_size, void* d_ws, size_t ws_size,
                              hipStream_t stream)
{
    const float* x = (const float*)d_in[0];
    const float* Wih[2][2]; const float* Whh[2][2]; const float* bih[2][2]; const float* bhh[2][2];
    int idx = 1;
    for (int l = 0; l < 2; ++l)
        for (int d = 0; d < 2; ++d) {
            Wih[l][d] = (const float*)d_in[idx++];
            Whh[l][d] = (const float*)d_in[idx++];
            bih[l][d] = (const float*)d_in[idx++];
            bhh[l][d] = (const float*)d_in[idx++];
        }
    const float* norm_w = (const float*)d_in[17];
    const float* ipw    = (const float*)d_in[18];
    const float* cw     = (const float*)d_in[19];
    const float* cbp    = (const float*)d_in[20];
    const float* xpw    = (const float*)d_in[21];
    const float* dpw    = (const float*)d_in[22];
    const float* dpb    = (const float*)d_in[23];
    const float* Alog   = (const float*)d_in[24];
    const float* Dparam = (const float*)d_in[25];
    const float* opw    = (const float*)d_in[26];
    const float* fcw    = (const float*)d_in[27];
    const float* fcb    = (const float*)d_in[28];

    const int M = BB * LL;                           // 32768
    const size_t SZ_H  = (size_t)M * DMODEL;
    const size_t SZ_E  = (size_t)M * EDIM;
    const size_t SZ_SH = (size_t)M * 70;

    const size_t need_min = (SZ_H + SZ_E + SZ_SH + (size_t)M) * sizeof(float);
    if (ws_size < need_min) {
        diag_k<<<(out_size + 63) / 64, 64, 0, stream>>>((float*)d_out, out_size,
                                                        (float)((double)ws_size / 1048576.0));
        return;
    }

    float* ws  = (float*)d_ws;
    float* H2  = ws;                 // [M][96]
    float* E2  = H2 + SZ_H;          // [M][768]
    float* SH  = E2 + SZ_E;          // DBC
    float* RSb = SH + SZ_SH;         // [M]

    float* XG  = E2;                          // [2][M][192] (LSTM phase alias)
    float* H1L = E2 + (size_t)2 * M * GH;     // [M][96]

    dim3 blk(256);

    // ---- LSTM layer 0
    dim3 g_xg(M / GBM, 2);
    gemm_bt<<<g_xg, blk, 0, stream>>>(x, 6, 0, Wih[0][0], bih[0][0], nullptr, nullptr, 0, nullptr, XG,                 GH, 0, M, GH, 6, 0);
    gemm_bt<<<g_xg, blk, 0, stream>>>(x, 6, 0, Wih[0][1], bih[0][1], nullptr, nullptr, 0, nullptr, XG + (size_t)M*GH, GH, 0, M, GH, 6, 0);
    lstm_scan<<<32, 64, 0, stream>>>(XG, Whh[0][0], bhh[0][0], Whh[0][1], bhh[0][1], H1L);
    // ---- LSTM layer 1
    gemm_bt<<<g_xg, blk, 0, stream>>>(H1L, DMODEL, 0, Wih[1][0], bih[1][0], nullptr, nullptr, 0, nullptr, XG,                 GH, 0, M, GH, DMODEL, 0);
    gemm_bt<<<g_xg, blk, 0, stream>>>(H1L, DMODEL, 0, Wih[1][1], bih[1][1], nullptr, nullptr, 0, nullptr, XG + (size_t)M*GH, GH, 0, M, GH, DMODEL, 0);
    lstm_scan<<<32, 64, 0, stream>>>(XG, Whh[1][0], bhh[1][0], Whh[1][1], bhh[1][1], H2);

    // ---- Mamba blocks
    for (int l = 0; l < 2; ++l) {
        const float* nw  = norm_w + (size_t)l * DMODEL;
        const float* ipl = ipw + (size_t)l * 2 * EDIM * DMODEL;
        const float* cwl = cw  + (size_t)l * EDIM * 16;
        const float* cbl = cbp + (size_t)l * EDIM;

        rms_rs_k<<<M / 4, blk, 0, stream>>>(H2, RSb);

        // fused rmsnorm + in_proj(half1) + conv + silu -> E2
        ipconv_k<<<dim3(LL / 64, EDIM / 64, BB), 320, 0, stream>>>(
            H2, RSb, nw, ipl, cwl, cbl, E2);

        // dbc = xm @ xpw.T (full M) -> SH
        gemm_bt<<<dim3(M / GBM, 1), blk, 0, stream>>>(E2, EDIM, 0, xpw + (size_t)l * 70 * EDIM,
                                                      nullptr, nullptr, nullptr, 0, nullptr,
                                                      SH, 70, 0, M, 70, EDIM, 0);
        // selective scan, in place over E2
        scan_k<<<(BB * EDIM) / 64, blk, 0, stream>>>(E2, SH,
            dpw + (size_t)l * EDIM * 6, dpb + (size_t)l * EDIM,
            Alog + (size_t)l * EDIM * NST, Dparam + (size_t)l * EDIM, E2);

        // z-GEMM with fused gate epilogue: E2 = E2 * silu(rmsnorm(H2)@ipw2.T)
        gemm_bt<<<dim3(M / GBM, EDIM / GBN), blk, 0, stream>>>(H2, DMODEL, 0,
                                               ipl + (size_t)EDIM * DMODEL,
                                               nullptr, E2, RSb, 0, nw,
                                               E2, EDIM, 0, M, EDIM, DMODEL, 1);

        // out_proj + residual (in place into H2)
        gemm_bt<<<dim3(M / GBM, 1), blk, 0, stream>>>(E2, EDIM, 0, opw + (size_t)l * DMODEL * EDIM,
                                                      nullptr, H2, nullptr, 0, nullptr,
                                                      H2, DMODEL, 0, M, DMODEL, EDIM, 0);
    }

    // ---- final FC on last timestep
    gemm_bt<<<dim3(1, 1), blk, 0, stream>>>(H2 + (size_t)(LL - 1) * DMODEL, (size_t)LL * DMODEL, 0,
                                            fcw, fcb, nullptr, nullptr, 0, nullptr,
                                            (float*)d_out, 4, 0, BB, 4, DMODEL, 0);
}

// Round 13
// 5831.770 us; speedup vs baseline: 1.0893x; 1.0893x over previous
//
#include <hip/hip_runtime.h>
#include <cstdint>
#include <cstddef>

#define BB 16
#define LL 2048
#define HME 48
#define GH 192
#define DMODEL 96
#define EDIM 768
#define NST 32

static __device__ __forceinline__ float fsig(float x) { return 1.f / (1.f + __expf(-x)); }
static __device__ __forceinline__ float ftanh(float x) { return 1.f - 2.f / (__expf(2.f * x) + 1.f); }
static __device__ __forceinline__ float siluf_(float x) { return x / (1.f + __expf(-x)); }

static __device__ __forceinline__ float rlane(float v, int i) {
    return __int_as_float(__builtin_amdgcn_readlane(__float_as_int(v), i));
}

static __device__ __forceinline__ void gload_lds16(const float* g, float* s) {
    __builtin_amdgcn_global_load_lds(
        (const __attribute__((address_space(1))) void*)g,
        (__attribute__((address_space(3))) void*)s, 16, 0, 0);
}

// ---------------------------------------------------------------- diag
__global__ void diag_k(float* o, int n, float v) {
    int i = blockIdx.x * 64 + threadIdx.x;
    if (i < n) o[i] = v;
}

// ---------------------------------------------------------------- GEMM
// emode 0: C = acc (+bias) (+res);  emode 1: C = res * silu(acc)
// Ahat[m][k] = A[m][k] * (RS ? RS[m]*NW[k] : 1)
#define GBM 128
#define GBN 128
#define GBK 16
__global__ __launch_bounds__(256) void gemm_bt(
    const float* __restrict__ A, size_t lda, size_t zsA,
    const float* __restrict__ W,
    const float* __restrict__ bias,
    const float* __restrict__ res,
    const float* __restrict__ RS, size_t zsRS,
    const float* __restrict__ NW,
    float* __restrict__ C, size_t ldc, size_t zsC,
    int M, int N, int K, int emode)
{
    A += (size_t)blockIdx.z * zsA;
    C += (size_t)blockIdx.z * zsC;
    if (RS) RS += (size_t)blockIdx.z * zsRS;
    __shared__ __align__(16) float As[GBK][GBM + 4];
    __shared__ __align__(16) float Ws[GBK][GBN + 4];
    int bm = blockIdx.x * GBM, bn = blockIdx.y * GBN;
    int tid = threadIdx.x;
    int tx = tid & 15, ty = tid >> 4;
    int lk = tid & 15;
    int lm = tid >> 4;
    float acc[8][8] = {};
    for (int k0 = 0; k0 < K; k0 += GBK) {
        #pragma unroll
        for (int p = 0; p < 8; ++p) {
            int m = lm + p * 16;
            int gm = bm + m, gk = k0 + lk;
            float aval = 0.f;
            if (gm < M && gk < K) {
                aval = A[(size_t)gm * lda + gk];
                if (RS) aval *= RS[gm] * NW[gk];
            }
            As[lk][m] = aval;
            int gn = bn + m;
            Ws[lk][m] = (gn < N && gk < K) ? W[(size_t)gn * K + gk] : 0.f;
        }
        __syncthreads();
        #pragma unroll
        for (int k = 0; k < GBK; ++k) {
            float av[8], bv[8];
            #pragma unroll
            for (int i = 0; i < 8; i += 4) {
                float4 t4 = *(const float4*)&As[k][ty * 8 + i];
                av[i] = t4.x; av[i+1] = t4.y; av[i+2] = t4.z; av[i+3] = t4.w;
            }
            #pragma unroll
            for (int jj = 0; jj < 8; jj += 4) {
                float4 t4 = *(const float4*)&Ws[k][tx * 8 + jj];
                bv[jj] = t4.x; bv[jj+1] = t4.y; bv[jj+2] = t4.z; bv[jj+3] = t4.w;
            }
            #pragma unroll
            for (int i = 0; i < 8; ++i)
                #pragma unroll
                for (int jj = 0; jj < 8; ++jj)
                    acc[i][jj] = fmaf(av[i], bv[jj], acc[i][jj]);
        }
        __syncthreads();
    }
    #pragma unroll
    for (int i = 0; i < 8; ++i) {
        int gm = bm + ty * 8 + i;
        if (gm >= M) continue;
        #pragma unroll
        for (int jj = 0; jj < 8; ++jj) {
            int gn = bn + tx * 8 + jj;
            if (gn >= N) continue;
            float v = acc[i][jj];
            if (emode == 0) {
                if (bias) v += bias[gn];
                if (res)  v += res[(size_t)gm * ldc + gn];
            } else {
                v = res[(size_t)gm * ldc + gn] * siluf_(v);
            }
            C[(size_t)gm * ldc + gn] = v;
        }
    }
}

// ---------------------------------------------------------------- LSTM scan v9 (r11 exact -- 1365us, best measured)
__global__ __launch_bounds__(64)
__attribute__((amdgpu_waves_per_eu(1, 1)))
void lstm_scan(
    const float* __restrict__ xg,        // [2][B][L][192]
    const float* __restrict__ WhhF, const float* __restrict__ bhhF,
    const float* __restrict__ WhhB, const float* __restrict__ bhhB,
    float* __restrict__ hout)            // [B][L][96]
{
    __shared__ __align__(16) float xs[2][64 * GH];   // 96 KB
    int blk = blockIdx.x;
    int b = blk >> 1, d = blk & 1;
    const float* W  = d ? WhhB : WhhF;
    const float* bh = d ? bhhB : bhhF;
    int l = threadIdx.x;

    float w0[HME], w1[HME], w2[HME];
    #pragma unroll
    for (int i = 0; i < HME; i += 4) {
        float4 t;
        t = *(const float4*)(W + (size_t)l * HME + i);
        w0[i] = t.x; w0[i+1] = t.y; w0[i+2] = t.z; w0[i+3] = t.w;
        t = *(const float4*)(W + (size_t)(64 + l) * HME + i);
        w1[i] = t.x; w1[i+1] = t.y; w1[i+2] = t.z; w1[i+3] = t.w;
        t = *(const float4*)(W + (size_t)(128 + l) * HME + i);
        w2[i] = t.x; w2[i+1] = t.y; w2[i+2] = t.z; w2[i+3] = t.w;
    }
    float b0 = bh[l], b1 = bh[64 + l], b2 = bh[128 + l];

    const float* xgp = xg + (size_t)(d * BB + b) * LL * GH;
    float hh = 0.f, c = 0.f;

    int sf = (l < 16) ? (48 + l) : (l - 16);
    int sg = (l < 32) ? (32 + l) : (l - 32);
    int so_ = (16 + l) & 63;

    const int NCHK = LL / 64;            // 32

    {
        const float* src = xgp + (size_t)(d ? (LL - 64) : 0) * GH;
        #pragma unroll
        for (int k = 0; k < 48; ++k)
            gload_lds16(src + k * 256 + l * 4, &xs[0][k * 256]);
    }
    asm volatile("s_waitcnt vmcnt(0)");
    __syncthreads();

    for (int cc = 0; cc < NCHK; ++cc) {
        const float* xc = &xs[cc & 1][0];
        if (cc + 1 < NCHK) {
            const float* src = xgp + (size_t)(d ? (LL - 64 * (cc + 2)) : (64 * (cc + 1))) * GH;
            float* dst = &xs[(cc + 1) & 1][0];
            #pragma unroll
            for (int k = 0; k < 48; ++k)
                gload_lds16(src + k * 256 + l * 4, dst + k * 256);
        }
        int bs = d ? (LL - 64 * (cc + 1)) : (64 * cc);
        int toff = d ? 63 : 0;
        int dt = d ? -1 : 1;
        float q0 = xc[toff * GH + l];
        float q1 = xc[toff * GH + 64 + l];
        float q2 = xc[toff * GH + 128 + l];
        for (int s = 0; s < 64; ++s) {
            float g0 = q0 + b0, g1 = q1 + b1, g2 = q2 + b2;
            if (s + 1 < 64) {
                int tn = toff + dt;
                q0 = xc[tn * GH + l];
                q1 = xc[tn * GH + 64 + l];
                q2 = xc[tn * GH + 128 + l];
            }
            #pragma unroll
            for (int i = 0; i < HME; ++i) {
                float hv = rlane(hh, i);
                g0 = fmaf(w0[i], hv, g0);
                g1 = fmaf(w1[i], hv, g1);
                g2 = fmaf(w2[i], hv, g2);
            }
            float a0 = fsig(g0);
            float a1 = (l < 32) ? fsig(g1) : ftanh(g1);
            float a2 = (l < 16) ? ftanh(g2) : fsig(g2);
            float gfA = __shfl(a0, sf);
            float gfB = __shfl(a1, sf);
            float ggA = __shfl(a1, sg);
            float ggB = __shfl(a2, sg);
            float go  = __shfl(a2, so_);
            float gf = (l < 16) ? gfA : gfB;
            float gg = (l < 32) ? ggA : ggB;
            c = fmaf(gf, c, a0 * gg);
            hh = go * ftanh(c);
            if (l < HME)
                hout[((size_t)b * LL + bs + toff) * DMODEL + d * HME + l] = hh;
            toff += dt;
        }
        asm volatile("s_waitcnt vmcnt(0)");
        __syncthreads();
    }
}

// ---------------------------------------------------------------- RMS per-row scale
__global__ __launch_bounds__(256) void rms_rs_k(
    const float* __restrict__ X, float* __restrict__ RS)
{
    int row = blockIdx.x * 4 + (threadIdx.x >> 6);
    int lane = threadIdx.x & 63;
    const float* xr = X + (size_t)row * DMODEL;
    float v0 = xr[lane];
    float v1 = (lane < 32) ? xr[64 + lane] : 0.f;
    float s = v0 * v0 + v1 * v1;
    #pragma unroll
    for (int dd = 1; dd < 64; dd <<= 1) s += __shfl_xor(s, dd);
    if (lane == 0) RS[row] = 1.f / sqrtf(s * (1.f / 96.f) + 1e-5f);
}

// ---------------------------------------------------------------- depthwise causal conv K=16 + bias + silu (r11 exact)
__global__ __launch_bounds__(256) void conv_silu_k(
    const float* __restrict__ IP, size_t zsIn,
    const float* __restrict__ cw,   // [768][16]
    const float* __restrict__ cb,   // [768]
    float* __restrict__ XMo, size_t zsOut)
{
    IP  += (size_t)blockIdx.z * zsIn;
    XMo += (size_t)blockIdx.z * zsOut;
    __shared__ float xs[79][64];
    __shared__ float wsh[64][17];
    int t0 = blockIdx.x * 64, c0 = blockIdx.y * 64;
    int tid = threadIdx.x;
    int cl = tid & 63, ts = tid >> 6;
    for (int i = tid; i < 64 * 16; i += 256)
        wsh[i >> 4][i & 15] = cw[(size_t)(c0 + (i >> 4)) * 16 + (i & 15)];
    for (int r = ts; r < 79; r += 4) {
        int tgl = t0 - 15 + r;
        xs[r][cl] = (tgl >= 0) ? IP[(size_t)tgl * EDIM + c0 + cl] : 0.f;
    }
    __syncthreads();
    float bias = cb[c0 + cl];
    for (int i = 0; i < 16; ++i) {
        int tl = ts * 16 + i;
        float acc = bias;
        #pragma unroll
        for (int k = 0; k < 16; ++k) acc = fmaf(wsh[cl][k], xs[tl + k][cl], acc);
        XMo[(size_t)(t0 + tl) * EDIM + c0 + cl] = siluf_(acc);
    }
}

// ---------------------------------------------------------------- selective scan v4
// v3 + vectorized LDS layout: DBC rows repacked at staging time --
// dt[0..5] | B at [8..39] | C at [40..71], row stride 76 (all per-group
// float4 slots 16B-aligned since n0 in {0,8,16,24}). Per step: 23 scalar
// ds_read_b32 -> 5x ds_read_b128 + 3x b32 (the dominant per-step issue cost).
#define SCH 16
#define DROW 76
__global__ __launch_bounds__(256) void scan_k(
    const float* __restrict__ XM,    // [B][L][768]
    const float* __restrict__ DBC,   // [B][L][70]
    const float* __restrict__ dpw,   // [768][6]
    const float* __restrict__ dpb,   // [768]
    const float* __restrict__ Alog,  // [768][32]
    const float* __restrict__ Dp,    // [768]
    float* Y)                        // [B][L][768]
{
    __shared__ __align__(16) float xs[2][SCH][64];
    __shared__ __align__(16) float dsh[2][SCH][DROW];
    int tid = threadIdx.x;
    int lane = tid & 63, wv = tid >> 6;
    int esub = lane & 15, nl = lane >> 4, n0 = nl * 8;
    int ch0 = blockIdx.x * 64;
    int b = ch0 / EDIM;
    int ebase = ch0 % EDIM;
    int e = ebase + wv * 16 + esub;

    float An[8], h[8], dw[6];
    #pragma unroll
    for (int i = 0; i < 8; ++i) { An[i] = -expf(Alog[(size_t)e * NST + n0 + i]); h[i] = 0.f; }
    #pragma unroll
    for (int r = 0; r < 6; ++r) dw[r] = dpw[(size_t)e * 6 + r];
    float db = dpb[e], Dpe = Dp[e];

    const float* xbase = XM  + ((size_t)b * LL) * EDIM + ebase;
    const float* dbase = DBC + ((size_t)b * LL) * 70;
    float* ybase = Y + ((size_t)b * LL) * EDIM + e;

    int srow = tid >> 4, scol = (tid & 15) * 4;
    float4 px;
    float pd[5];

    // repack target column for DBC element c (0..69)
    #define NEWC(c) ((c) < 6 ? (c) : ((c) < 38 ? 8 + (c) - 6 : 40 + (c) - 38))

    // stage chunk 0
    px = *(const float4*)(xbase + (size_t)srow * EDIM + scol);
    #pragma unroll
    for (int k = 0; k < 5; ++k) {
        int i = tid + k * 256;
        pd[k] = (i < SCH * 70) ? dbase[i] : 0.f;
    }
    *(float4*)&xs[0][srow][scol] = px;
    #pragma unroll
    for (int k = 0; k < 5; ++k) {
        int i = tid + k * 256;
        if (i < SCH * 70) { int r = i / 70, c = i % 70; dsh[0][r][NEWC(c)] = pd[k]; }
    }
    __syncthreads();

    const int NCH = LL / SCH;   // 128
    for (int cc = 0; cc < NCH; ++cc) {
        int buf = cc & 1;
        if (cc + 1 < NCH) {
            size_t t0n = (size_t)(cc + 1) * SCH;
            px = *(const float4*)(xbase + (t0n + srow) * EDIM + scol);
            #pragma unroll
            for (int k = 0; k < 5; ++k) {
                int i = tid + k * 256;
                pd[k] = (i < SCH * 70) ? dbase[t0n * 70 + i] : 0.f;
            }
        }
        #pragma unroll 2
        for (int tl = 0; tl < SCH; ++tl) {
            const float* drow = &dsh[buf][tl][0];
            float4 dc0 = *(const float4*)&drow[0];
            float dc4 = drow[4], dc5 = drow[5];
            float4 B0 = *(const float4*)&drow[8 + n0];
            float4 B1 = *(const float4*)&drow[12 + n0];
            float4 C0 = *(const float4*)&drow[40 + n0];
            float4 C1 = *(const float4*)&drow[44 + n0];
            float x = xs[buf][tl][wv * 16 + esub];
            float draw = db;
            draw = fmaf(dw[0], dc0.x, draw);
            draw = fmaf(dw[1], dc0.y, draw);
            draw = fmaf(dw[2], dc0.z, draw);
            draw = fmaf(dw[3], dc0.w, draw);
            draw = fmaf(dw[4], dc4, draw);
            draw = fmaf(dw[5], dc5, draw);
            float delta = (draw > 20.f) ? draw : __logf(1.f + __expf(draw));
            float dx = delta * x;
            float y = 0.f;
            float Bv[8] = {B0.x, B0.y, B0.z, B0.w, B1.x, B1.y, B1.z, B1.w};
            float Cv[8] = {C0.x, C0.y, C0.z, C0.w, C1.x, C1.y, C1.z, C1.w};
            #pragma unroll
            for (int i = 0; i < 8; ++i) {
                float dA = __expf(delta * An[i]);
                h[i] = fmaf(dA, h[i], dx * Bv[i]);
                y = fmaf(h[i], Cv[i], y);
            }
            y += __shfl_xor(y, 16);
            y += __shfl_xor(y, 32);
            if (nl == 0) ybase[(size_t)(cc * SCH + tl) * EDIM] = fmaf(x, Dpe, y);
        }
        if (cc + 1 < NCH) {
            *(float4*)&xs[buf ^ 1][srow][scol] = px;
            #pragma unroll
            for (int k = 0; k < 5; ++k) {
                int i = tid + k * 256;
                if (i < SCH * 70) { int r = i / 70, c = i % 70; dsh[buf ^ 1][r][NEWC(c)] = pd[k]; }
            }
        }
        __syncthreads();
    }
    #undef NEWC
}

// ---------------------------------------------------------------- host
extern "C" void kernel_launch(void* const* d_in, const int* in_sizes, int n_in,
                              void* d_out, int out_size, void* d_ws, size_t ws_size,
                              hipStream_t stream)
{
    const float* x = (const float*)d_in[0];
    const float* Wih[2][2]; const float* Whh[2][2]; const float* bih[2][2]; const float* bhh[2][2];
    int idx = 1;
    for (int l = 0; l < 2; ++l)
        for (int d = 0; d < 2; ++d) {
            Wih[l][d] = (const float*)d_in[idx++];
            Whh[l][d] = (const float*)d_in[idx++];
            bih[l][d] = (const float*)d_in[idx++];
            bhh[l][d] = (const float*)d_in[idx++];
        }
    const float* norm_w = (const float*)d_in[17];
    const float* ipw    = (const float*)d_in[18];
    const float* cw     = (const float*)d_in[19];
    const float* cbp    = (const float*)d_in[20];
    const float* xpw    = (const float*)d_in[21];
    const float* dpw    = (const float*)d_in[22];
    const float* dpb    = (const float*)d_in[23];
    const float* Alog   = (const float*)d_in[24];
    const float* Dparam = (const float*)d_in[25];
    const float* opw    = (const float*)d_in[26];
    const float* fcw    = (const float*)d_in[27];
    const float* fcb    = (const float*)d_in[28];

    const int M = BB * LL;                           // 32768
    const size_t SZ_H  = (size_t)M * DMODEL;
    const size_t SZ_E  = (size_t)M * EDIM;
    const size_t BSTRIDE_H = (size_t)LL * DMODEL;
    const size_t BSTRIDE_E = (size_t)LL * EDIM;

    // adaptive chunk: SH holds max(M*70, cb*L*768) floats
    int cb = 1;
    size_t SZ_SH = (size_t)M * 70;
    {
        const int cand[4] = {16, 8, 4, 2};
        for (int ci = 0; ci < 4; ++ci) {
            size_t shf = (size_t)cand[ci] * BSTRIDE_E;
            if (shf < (size_t)M * 70) shf = (size_t)M * 70;
            size_t need = (SZ_H + SZ_E + shf + (size_t)M) * sizeof(float);
            if (need <= ws_size) { cb = cand[ci]; SZ_SH = shf; break; }
        }
    }
    const size_t need_min = (SZ_H + SZ_E + (size_t)M * 70 + (size_t)M) * sizeof(float);
    if (ws_size < need_min) {
        diag_k<<<(out_size + 63) / 64, 64, 0, stream>>>((float*)d_out, out_size,
                                                        (float)((double)ws_size / 1048576.0));
        return;
    }

    float* ws  = (float*)d_ws;
    float* H2  = ws;                 // [M][96]
    float* E2  = H2 + SZ_H;          // [M][768]
    float* SH  = E2 + SZ_E;          // chunked xm-raw / DBC
    float* RSb = SH + SZ_SH;         // [M]

    float* XG  = E2;                          // [2][M][192] (LSTM phase alias)
    float* H1L = E2 + (size_t)2 * M * GH;     // [M][96]

    dim3 blk(256);

    // ---- LSTM layer 0
    dim3 g_xg(M / GBM, 2);
    gemm_bt<<<g_xg, blk, 0, stream>>>(x, 6, 0, Wih[0][0], bih[0][0], nullptr, nullptr, 0, nullptr, XG,                 GH, 0, M, GH, 6, 0);
    gemm_bt<<<g_xg, blk, 0, stream>>>(x, 6, 0, Wih[0][1], bih[0][1], nullptr, nullptr, 0, nullptr, XG + (size_t)M*GH, GH, 0, M, GH, 6, 0);
    lstm_scan<<<32, 64, 0, stream>>>(XG, Whh[0][0], bhh[0][0], Whh[0][1], bhh[0][1], H1L);
    // ---- LSTM layer 1
    gemm_bt<<<g_xg, blk, 0, stream>>>(H1L, DMODEL, 0, Wih[1][0], bih[1][0], nullptr, nullptr, 0, nullptr, XG,                 GH, 0, M, GH, DMODEL, 0);
    gemm_bt<<<g_xg, blk, 0, stream>>>(H1L, DMODEL, 0, Wih[1][1], bih[1][1], nullptr, nullptr, 0, nullptr, XG + (size_t)M*GH, GH, 0, M, GH, DMODEL, 0);
    lstm_scan<<<32, 64, 0, stream>>>(XG, Whh[1][0], bhh[1][0], Whh[1][1], bhh[1][1], H2);

    // ---- Mamba blocks
    for (int l = 0; l < 2; ++l) {
        const float* nw  = norm_w + (size_t)l * DMODEL;
        const float* ipl = ipw + (size_t)l * 2 * EDIM * DMODEL;
        const float* cwl = cw  + (size_t)l * EDIM * 16;
        const float* cbl = cbp + (size_t)l * EDIM;

        rms_rs_k<<<M / 4, blk, 0, stream>>>(H2, RSb);

        // front-end per-chunk: xm = rmsnorm(H2)@ipw1.T -> SH ; conv+silu -> E2
        dim3 g_ipb(LL / GBM, EDIM / GBN, cb);
        dim3 g_cv(LL / 64, EDIM / 64, cb);
        for (int b0 = 0; b0 < BB; b0 += cb) {
            gemm_bt<<<g_ipb, blk, 0, stream>>>(H2 + b0 * BSTRIDE_H, DMODEL, BSTRIDE_H, ipl,
                                               nullptr, nullptr, RSb + (size_t)b0 * LL, LL, nw,
                                               SH, EDIM, BSTRIDE_E, LL, EDIM, DMODEL, 0);
            conv_silu_k<<<g_cv, blk, 0, stream>>>(SH, BSTRIDE_E, cwl, cbl,
                                                  E2 + b0 * BSTRIDE_E, BSTRIDE_E);
        }

        // dbc = xm @ xpw.T (full M) -> SH
        gemm_bt<<<dim3(M / GBM, 1), blk, 0, stream>>>(E2, EDIM, 0, xpw + (size_t)l * 70 * EDIM,
                                                      nullptr, nullptr, nullptr, 0, nullptr,
                                                      SH, 70, 0, M, 70, EDIM, 0);
        // selective scan, in place over E2
        scan_k<<<(BB * EDIM) / 64, blk, 0, stream>>>(E2, SH,
            dpw + (size_t)l * EDIM * 6, dpb + (size_t)l * EDIM,
            Alog + (size_t)l * EDIM * NST, Dparam + (size_t)l * EDIM, E2);

        // z-GEMM with fused gate epilogue: E2 = E2 * silu(rmsnorm(H2)@ipw2.T)
        gemm_bt<<<dim3(M / GBM, EDIM / GBN), blk, 0, stream>>>(H2, DMODEL, 0,
                                               ipl + (size_t)EDIM * DMODEL,
                                               nullptr, E2, RSb, 0, nw,
                                               E2, EDIM, 0, M, EDIM, DMODEL, 1);

        // out_proj + residual (in place into H2)
        gemm_bt<<<dim3(M / GBM, 1), blk, 0, stream>>>(E2, EDIM, 0, opw + (size_t)l * DMODEL * EDIM,
                                                      nullptr, H2, nullptr, 0, nullptr,
                                                      H2, DMODEL, 0, M, DMODEL, EDIM, 0);
    }

    // ---- final FC on last timestep
    gemm_bt<<<dim3(1, 1), blk, 0, stream>>>(H2 + (size_t)(LL - 1) * DMODEL, (size_t)LL * DMODEL, 0,
                                            fcw, fcb, nullptr, nullptr, 0, nullptr,
                                            (float*)d_out, 4, 0, BB, 4, DMODEL, 0);
}